// Round 11
// baseline (229.530 us; speedup 1.0000x reference)
//
#include <hip/hip_runtime.h>

typedef unsigned short u16;
typedef unsigned int u32;

typedef __bf16 bf16x8 __attribute__((ext_vector_type(8)));
typedef float f32x4 __attribute__((ext_vector_type(4)));

union FragI { int4 i; bf16x8 b; u16 u[8]; };

__device__ __forceinline__ u16 f2bf(float x) {
  u32 u = __float_as_uint(x);
  u32 r = (u + 0x7fffu + ((u >> 16) & 1u)) >> 16;
  return (u16)r;
}
__device__ __forceinline__ float tanh_fast(float x) {
  float e = __expf(2.0f * x);
  return 1.0f - __fdividef(2.0f, e + 1.0f);
}
__device__ __forceinline__ bf16x8 load_cvt8(const float* __restrict__ p) {
  float4 f0 = *(const float4*)p;
  float4 f1 = *(const float4*)(p + 4);
  union { bf16x8 b; u16 u[8]; } t;
  t.u[0] = f2bf(f0.x); t.u[1] = f2bf(f0.y); t.u[2] = f2bf(f0.z); t.u[3] = f2bf(f0.w);
  t.u[4] = f2bf(f1.x); t.u[5] = f2bf(f1.y); t.u[6] = f2bf(f1.z); t.u[7] = f2bf(f1.w);
  return t.b;
}

#define LOGITS_N 67108864

// ---------------- f32 -> bf16 conversion (W_out) ----------------
__global__ __launch_bounds__(256) void conv_v4(const float* __restrict__ in,
                                               u16* __restrict__ out, int n4) {
  int i = blockIdx.x * 256 + threadIdx.x;
  if (i >= n4) return;
  float4 f = ((const float4*)in)[i];
  union { u16 u[4]; int2 v; } o;
  o.u[0] = f2bf(f.x); o.u[1] = f2bf(f.y); o.u[2] = f2bf(f.z); o.u[3] = f2bf(f.w);
  ((int2*)out)[i] = o.v;
}

// W_dur [5][640] f32 -> padded bf16 [16][640] (rows 5..15 zero)
__global__ __launch_bounds__(256) void conv_wdur(const float* __restrict__ in,
                                                 u16* __restrict__ out) {
  int i = blockIdx.x * 256 + threadIdx.x;
  if (i < 16 * 640) out[i] = (i < 5 * 640) ? f2bf(in[i]) : (u16)0;
}

// ---------------- projection GEMM (f32 out; verified R1-R10) ----------------
__global__ __launch_bounds__(256) void proj_gemm(const float* __restrict__ A,
                                                 const float* __restrict__ Bw,
                                                 const float* __restrict__ bias,
                                                 float* __restrict__ C,
                                                 int M, int N, int K) {
  int tid = threadIdx.x;
  int lane = tid & 63, wid = tid >> 6;
  int m0 = blockIdx.x * 64, n0 = blockIdx.y * 64;
  int kper = K >> 2;
  int kbase = wid * kper;
  int ksteps = kper >> 5;
  int r16 = lane & 15, khi = (lane >> 4) * 8;

  f32x4 z = {0.f, 0.f, 0.f, 0.f};
  f32x4 acc[4][4];
  for (int i = 0; i < 4; ++i)
    for (int j = 0; j < 4; ++j) acc[i][j] = z;

  for (int ks = 0; ks < ksteps; ++ks) {
    int k = kbase + ks * 32 + khi;
    bf16x8 af[4], bf[4];
#pragma unroll
    for (int fm = 0; fm < 4; ++fm)
      af[fm] = load_cvt8(A + (size_t)(m0 + fm * 16 + r16) * K + k);
#pragma unroll
    for (int fn = 0; fn < 4; ++fn)
      bf[fn] = load_cvt8(Bw + (size_t)(n0 + fn * 16 + r16) * K + k);
#pragma unroll
    for (int fm = 0; fm < 4; ++fm)
#pragma unroll
      for (int fn = 0; fn < 4; ++fn)
        acc[fm][fn] = __builtin_amdgcn_mfma_f32_16x16x32_bf16(af[fm], bf[fn], acc[fm][fn], 0, 0, 0);
  }

  __shared__ float red[4][64][64];
#pragma unroll
  for (int fm = 0; fm < 4; ++fm)
#pragma unroll
    for (int fn = 0; fn < 4; ++fn)
#pragma unroll
      for (int i = 0; i < 4; ++i)
        red[wid][fm * 16 + (lane >> 4) * 4 + i][fn * 16 + r16] = acc[fm][fn][i];
  __syncthreads();
  for (int idx = tid; idx < 4096; idx += 256) {
    int r = idx >> 6, c = idx & 63;
    float s = red[0][r][c] + red[1][r][c] + red[2][r][c] + red[3][r][c] + bias[n0 + c];
    C[(size_t)(m0 + r) * N + n0 + c] = s;
  }
}

// ---------------- bt_fused2: block = (bt, N-half); A-panel in LDS; B reg-dbuf from L2 ----------------
// 512 thr / 8 waves; wave = 64 rows x 64 cols. A-panel 80 KB -> 2 blocks/CU (160 KB).
// Prologue: tanh(enc[bt]+pred[b,:]) once -> swizzled LDS. K-loop: no barriers; B-frags
// double-buffered in registers from L2-resident WoB (1.3 MB). Durations: wave 0 of
// half==0 blocks, post-epilogue, off the still-live LDS panel (reuses acc's dead regs).
// out: logits f32 [65536][1024] at 0, durations f32 [65536][5] at 67108864
__global__ __launch_bounds__(512, 4) void bt_fused2(const float* __restrict__ encP,
                                                    const float* __restrict__ predP,
                                                    const u16* __restrict__ WoB,
                                                    const u16* __restrict__ WdB,
                                                    const float* __restrict__ b_out,
                                                    const float* __restrict__ b_dur,
                                                    float* __restrict__ out) {
  __shared__ __align__(16) u16 As[64 * 640];  // 80 KiB exactly

  int tid = threadIdx.x;
  int lane = tid & 63, wid = tid >> 6;
  int bid = blockIdx.x;
  int swz = (bid & 7) * 256 + (bid >> 3);   // 2048 % 8 == 0 -> bijective XCD swizzle
  int half = swz & 1, bt = swz >> 1;
  int r16 = lane & 15, g4 = lane >> 4, khi8 = g4 * 8;
  int xr = r16 & 7;                          // (m*16+r16)&7 == r16&7 for all m
  int pb = (bt >> 8) * 64;

  // ---- prologue: build A-panel (tanh once), swizzled 16B chunks ----
  const float* encRow = encP + (size_t)bt * 640;
#pragma unroll
  for (int j = 0; j < 10; ++j) {
    int idx = j * 512 + tid;                 // 0..5119
    int row = idx / 80;
    int c = idx - row * 80;
    const float* ep = encRow + c * 8;
    const float* pp = predP + (size_t)(pb + row) * 640 + c * 8;
    float4 e0 = *(const float4*)ep;
    float4 e1 = *(const float4*)(ep + 4);
    float4 p0 = *(const float4*)pp;
    float4 p1 = *(const float4*)(pp + 4);
    FragI h;
    h.u[0] = f2bf(tanh_fast(e0.x + p0.x));
    h.u[1] = f2bf(tanh_fast(e0.y + p0.y));
    h.u[2] = f2bf(tanh_fast(e0.z + p0.z));
    h.u[3] = f2bf(tanh_fast(e0.w + p0.w));
    h.u[4] = f2bf(tanh_fast(e1.x + p1.x));
    h.u[5] = f2bf(tanh_fast(e1.y + p1.y));
    h.u[6] = f2bf(tanh_fast(e1.z + p1.z));
    h.u[7] = f2bf(tanh_fast(e1.w + p1.w));
    *(int4*)(As + row * 640 + ((c ^ (row & 7)) << 3)) = h.i;
  }
  __syncthreads();

  int colbase = (half << 9) + (wid << 6);
  const u16* Bp0 = WoB + (size_t)(colbase + 0 * 16 + r16) * 640 + khi8;
  const u16* Bp1 = WoB + (size_t)(colbase + 1 * 16 + r16) * 640 + khi8;
  const u16* Bp2 = WoB + (size_t)(colbase + 2 * 16 + r16) * 640 + khi8;
  const u16* Bp3 = WoB + (size_t)(colbase + 3 * 16 + r16) * 640 + khi8;

  f32x4 z = {0.f, 0.f, 0.f, 0.f};
  f32x4 acc[4][4];
#pragma unroll
  for (int i = 0; i < 4; ++i)
#pragma unroll
    for (int j = 0; j < 4; ++j) acc[i][j] = z;

  // A-frag LDS element offsets: rbase[m] + swizzled chunk (chunk = ko/8 + g4)
  int rb0 = (0 * 16 + r16) * 640;
  // m stride = 16*640 = 10240 elems -> 20480 B: folds into ds_read offset immediates

  FragI b0[4], b1[4];
  b0[0].i = *(const int4*)(Bp0);
  b0[1].i = *(const int4*)(Bp1);
  b0[2].i = *(const int4*)(Bp2);
  b0[3].i = *(const int4*)(Bp3);

#define MFMA4(M, AQ, BB) \
  acc[M][0] = __builtin_amdgcn_mfma_f32_16x16x32_bf16((AQ).b, (BB)[0].b, acc[M][0], 0, 0, 0); \
  acc[M][1] = __builtin_amdgcn_mfma_f32_16x16x32_bf16((AQ).b, (BB)[1].b, acc[M][1], 0, 0, 0); \
  acc[M][2] = __builtin_amdgcn_mfma_f32_16x16x32_bf16((AQ).b, (BB)[2].b, acc[M][2], 0, 0, 0); \
  acc[M][3] = __builtin_amdgcn_mfma_f32_16x16x32_bf16((AQ).b, (BB)[3].b, acc[M][3], 0, 0, 0);

#define ARD(M, CS) (*(const int4*)(As + rb0 + (M) * 10240 + (CS)))

  for (int ko = 0; ko < 640; ko += 64) {
    // ---- half A: compute with b0 (k=[ko,ko+32)), prefetch b1 (k=[ko+32,ko+64)) ----
    b1[0].i = *(const int4*)(Bp0 + ko + 32);
    b1[1].i = *(const int4*)(Bp1 + ko + 32);
    b1[2].i = *(const int4*)(Bp2 + ko + 32);
    b1[3].i = *(const int4*)(Bp3 + ko + 32);
    {
      int cs = ((((ko >> 3) + g4) ^ xr) << 3);
      FragI aqa, aqb;
      aqa.i = ARD(0, cs);
      aqb.i = ARD(1, cs);
      MFMA4(0, aqa, b0); aqa.i = ARD(2, cs);
      MFMA4(1, aqb, b0); aqb.i = ARD(3, cs);
      MFMA4(2, aqa, b0);
      MFMA4(3, aqb, b0);
    }
    // ---- half B: compute with b1 (k=[ko+32,ko+64)), prefetch b0 (k=[ko+64,ko+96)) ----
    if (ko < 576) {
      b0[0].i = *(const int4*)(Bp0 + ko + 64);
      b0[1].i = *(const int4*)(Bp1 + ko + 64);
      b0[2].i = *(const int4*)(Bp2 + ko + 64);
      b0[3].i = *(const int4*)(Bp3 + ko + 64);
    }
    {
      int cs = ((((ko >> 3) + 4 + g4) ^ xr) << 3);
      FragI aqa, aqb;
      aqa.i = ARD(0, cs);
      aqb.i = ARD(1, cs);
      MFMA4(0, aqa, b1); aqa.i = ARD(2, cs);
      MFMA4(1, aqb, b1); aqb.i = ARD(3, cs);
      MFMA4(2, aqa, b1);
      MFMA4(3, aqb, b1);
    }
  }

  // ---- epilogue: bias + store logits ----
  size_t rowbase = (size_t)bt * 64;
#pragma unroll
  for (int fn = 0; fn < 4; ++fn) {
    int col = colbase + fn * 16 + r16;
    float bo = b_out[col];
#pragma unroll
    for (int m = 0; m < 4; ++m) {
      size_t row = rowbase + m * 16 + g4 * 4;
#pragma unroll
      for (int i = 0; i < 4; ++i)
        out[(row + i) * 1024 + col] = acc[m][fn][i] + bo;
    }
  }

  // ---- durations: wave 0 of half==0 blocks, off the live LDS panel ----
  if (half == 0 && wid == 0) {
    f32x4 dacc0 = z, dacc1 = z, dacc2 = z, dacc3 = z;
    const u16* Wp = WdB + (size_t)r16 * 640 + khi8;
    for (int ko = 0; ko < 640; ko += 32) {
      FragI wd, am;
      wd.i = *(const int4*)(Wp + ko);
      int cs = ((((ko >> 3) + g4) ^ xr) << 3);
      am.i = ARD(0, cs);
      dacc0 = __builtin_amdgcn_mfma_f32_16x16x32_bf16(am.b, wd.b, dacc0, 0, 0, 0);
      am.i = ARD(1, cs);
      dacc1 = __builtin_amdgcn_mfma_f32_16x16x32_bf16(am.b, wd.b, dacc1, 0, 0, 0);
      am.i = ARD(2, cs);
      dacc2 = __builtin_amdgcn_mfma_f32_16x16x32_bf16(am.b, wd.b, dacc2, 0, 0, 0);
      am.i = ARD(3, cs);
      dacc3 = __builtin_amdgcn_mfma_f32_16x16x32_bf16(am.b, wd.b, dacc3, 0, 0, 0);
    }
    if (r16 < 5) {
      float bd = b_dur[r16];
      f32x4 dv[4] = {dacc0, dacc1, dacc2, dacc3};
#pragma unroll
      for (int m = 0; m < 4; ++m) {
        size_t row = rowbase + m * 16 + g4 * 4;
#pragma unroll
        for (int i = 0; i < 4; ++i)
          out[LOGITS_N + (row + i) * 5 + r16] = dv[m][i] + bd;
      }
    }
  }
#undef MFMA4
#undef ARD
}

extern "C" void kernel_launch(void* const* d_in, const int* in_sizes, int n_in,
                              void* d_out, int out_size, void* d_ws, size_t ws_size,
                              hipStream_t stream) {
  const float* encoder   = (const float*)d_in[0];
  const float* predictor = (const float*)d_in[1];
  const float* W_enc = (const float*)d_in[2];
  const float* b_enc = (const float*)d_in[3];
  const float* W_pred = (const float*)d_in[4];
  const float* b_pred = (const float*)d_in[5];
  const float* W_out = (const float*)d_in[6];
  const float* b_out = (const float*)d_in[7];
  const float* W_dur = (const float*)d_in[8];
  const float* b_dur = (const float*)d_in[9];
  float* out = (float*)d_out;

  char* ws = (char*)d_ws;
  u16* WoB    = (u16*)(ws);                // 1024*640*2 = 1,310,720 B
  u16* WdB    = (u16*)(ws + 1310720);      // 16*640*2   =     20,480 B
  float* encP = (float*)(ws + 1331200);    // 1024*640*4 =  2,621,440 B
  float* predP= (float*)(ws + 3952640);    // 256*640*4  =    655,360 B

  conv_v4<<<640, 256, 0, stream>>>(W_out, WoB, 163840);
  conv_wdur<<<40, 256, 0, stream>>>(W_dur, WdB);
  proj_gemm<<<dim3(16, 10), 256, 0, stream>>>(encoder, W_enc, b_enc, encP, 1024, 640, 1024);
  proj_gemm<<<dim3(4, 10), 256, 0, stream>>>(predictor, W_pred, b_pred, predP, 256, 640, 640);
  bt_fused2<<<2048, 512, 0, stream>>>(encP, predP, WoB, WdB, b_out, b_dur, out);
}